// Round 2
// baseline (2974.572 us; speedup 1.0000x reference)
//
#include <hip/hip_runtime.h>
#include <stdint.h>

#define T_ 512
#define B_ 64
#define H_ 512
#define L_ 2
#define TBH (T_*B_*H_)   // 16777216
#define BH  (B_*H_)      // 32768

typedef float    f32x4 __attribute__((ext_vector_type(4)));
typedef short    s16x8 __attribute__((ext_vector_type(8)));
typedef short    s16x4 __attribute__((ext_vector_type(4)));
typedef _Float16 h2    __attribute__((ext_vector_type(2)));

static __device__ __forceinline__ short f2bf(float f) {
  uint32_t u = __float_as_uint(f);
  u = (u + 0x7fffu + ((u >> 16) & 1u)) >> 16;  // RNE
  return (short)u;
}

static __device__ __forceinline__ float fdot2(h2 a, h2 b, float c) {
#if __has_builtin(__builtin_amdgcn_fdot2)
  return __builtin_amdgcn_fdot2(a, b, c, false);
#else
  return c + (float)a[0] * (float)b[0] + (float)a[1] * (float)b[1];
#endif
}

template <int IMM>
static __device__ __forceinline__ float swz(float v) {
  return __int_as_float(__builtin_amdgcn_ds_swizzle(__float_as_int(v), IMM));
}

// ---------------------------------------------------------------------------
// GEMM: Out[m,n] = sum_k In[m,k]*W[n,k] + bi[n] + bh[n]
// M=32768 (=T*B), N=512, K=512. bf16 MFMA 16x16x32, 128x128 tile, 4 waves.
// ---------------------------------------------------------------------------
__global__ __launch_bounds__(256, 4)
void gemm_xw(const float* __restrict__ In, const float* __restrict__ W,
             const float* __restrict__ bi, const float* __restrict__ bh,
             float* __restrict__ Out) {
  constexpr int LDT = 40;  // padded LDS stride in halves (80B: 16B-aligned, 2-way max)
  __shared__ short As[128 * LDT];
  __shared__ short Bs[128 * LDT];

  const int tid  = threadIdx.x;
  const int m0   = blockIdx.x * 128;
  const int n0   = blockIdx.y * 128;
  const int wave = tid >> 6, lane = tid & 63;
  const int wm   = (wave >> 1) * 64;   // wave M offset in tile
  const int wn   = (wave & 1) * 64;    // wave N offset in tile
  const int quad = lane >> 4, tq = lane & 15;

  f32x4 acc[4][4] = {};

  for (int k0 = 0; k0 < 512; k0 += 32) {
    #pragma unroll
    for (int v = 0; v < 4; ++v) {
      int idx = v * 256 + tid;            // 0..1023 covers 128 rows x 8 float4
      int r = idx >> 3, cc = (idx & 7) * 4;
      f32x4 a = *(const f32x4*)(In + (size_t)(m0 + r) * 512 + k0 + cc);
      s16x4 ap = { f2bf(a.x), f2bf(a.y), f2bf(a.z), f2bf(a.w) };
      *(s16x4*)(&As[r * LDT + cc]) = ap;
      f32x4 b = *(const f32x4*)(W + (size_t)(n0 + r) * 512 + k0 + cc);
      s16x4 bp = { f2bf(b.x), f2bf(b.y), f2bf(b.z), f2bf(b.w) };
      *(s16x4*)(&Bs[r * LDT + cc]) = bp;
    }
    __syncthreads();

    s16x8 af[4], bfr[4];
    #pragma unroll
    for (int mf = 0; mf < 4; ++mf)
      af[mf] = *(const s16x8*)(&As[(wm + mf * 16 + tq) * LDT + quad * 8]);
    #pragma unroll
    for (int nf = 0; nf < 4; ++nf)
      bfr[nf] = *(const s16x8*)(&Bs[(wn + nf * 16 + tq) * LDT + quad * 8]);
    #pragma unroll
    for (int mf = 0; mf < 4; ++mf)
      #pragma unroll
      for (int nf = 0; nf < 4; ++nf)
        acc[mf][nf] = __builtin_amdgcn_mfma_f32_16x16x32_bf16(
            af[mf], bfr[nf], acc[mf][nf], 0, 0, 0);
    __syncthreads();
  }

  #pragma unroll
  for (int nf = 0; nf < 4; ++nf) {
    int col = n0 + wn + nf * 16 + tq;
    float bv = bi[col] + bh[col];
    #pragma unroll
    for (int mf = 0; mf < 4; ++mf) {
      #pragma unroll
      for (int r = 0; r < 4; ++r) {
        int row = m0 + wm + mf * 16 + quad * 4 + r;
        Out[(size_t)row * 512 + col] = acc[mf][nf][r] + bv;
      }
    }
  }
}

// ---------------------------------------------------------------------------
// Recurrence for one layer: one workgroup per batch element, W_hh in VGPRs
// (fp16). Thread t = (rg=t>>3)*8 + (c=t&7): rows rg*8..rg*8+7, col chunk
// c*64..c*64+63. Per step: 256 v_dot2 + ds_swizzle butterfly over the 8
// consecutive lanes sharing a row-group -> thread t owns row t.
// xw buffer is overwritten in place with y.
// ---------------------------------------------------------------------------
__global__ __launch_bounds__(512, 1)
void recur(float* __restrict__ xw_y, const float* __restrict__ h0,
           const float* __restrict__ Wh, float* __restrict__ hn) {
  const int b   = blockIdx.x;
  const int tid = threadIdx.x;
  const int c   = tid & 7;
  const int rg  = tid >> 3;

  // chunk ci lives at offset ci*72 halves (144B): bank starts 0,4,...,28
  __shared__ _Float16 hbuf[2][8 * 72];

  // --- load weights into registers (fp16, 256 VGPRs) ---
  h2 wreg[8][32];
  #pragma unroll
  for (int k = 0; k < 8; ++k) {
    const float* wrow = Wh + (size_t)(rg * 8 + k) * 512 + c * 64;
    #pragma unroll
    for (int u = 0; u < 16; ++u) {
      f32x4 w4 = *(const f32x4*)(wrow + u * 4);
      wreg[k][u * 2]     = h2{(_Float16)w4.x, (_Float16)w4.y};
      wreg[k][u * 2 + 1] = h2{(_Float16)w4.z, (_Float16)w4.w};
    }
  }

  hbuf[0][(tid >> 6) * 72 + (tid & 63)] = (_Float16)h0[b * 512 + tid];
  __syncthreads();

  float hlast = 0.f;
  for (int t = 0; t < T_; ++t) {
    const int cur = t & 1, nxt = cur ^ 1;
    float xwv = xw_y[(size_t)t * BH + b * 512 + tid];

    const _Float16* hc = &hbuf[cur][c * 72];
    uint4 hv[8];
    #pragma unroll
    for (int u = 0; u < 8; ++u) hv[u] = *(const uint4*)(hc + u * 8);

    float acc[8] = {0, 0, 0, 0, 0, 0, 0, 0};
    #pragma unroll
    for (int u = 0; u < 8; ++u) {
      h2 p0 = __builtin_bit_cast(h2, hv[u].x);
      h2 p1 = __builtin_bit_cast(h2, hv[u].y);
      h2 p2 = __builtin_bit_cast(h2, hv[u].z);
      h2 p3 = __builtin_bit_cast(h2, hv[u].w);
      #pragma unroll
      for (int k = 0; k < 8; ++k) {
        acc[k] = fdot2(wreg[k][u * 4 + 0], p0, acc[k]);
        acc[k] = fdot2(wreg[k][u * 4 + 1], p1, acc[k]);
        acc[k] = fdot2(wreg[k][u * 4 + 2], p2, acc[k]);
        acc[k] = fdot2(wreg[k][u * 4 + 3], p3, acc[k]);
      }
    }

    // butterfly reduce across the 8 lanes of the row-group (lane xor 1,2,4)
    float r1[4];
    #pragma unroll
    for (int p = 0; p < 4; ++p) {
      float send = (c & 1) ? acc[2 * p] : acc[2 * p + 1];
      float recv = swz<0x041F>(send);
      float keep = (c & 1) ? acc[2 * p + 1] : acc[2 * p];
      r1[p] = keep + recv;
    }
    float r2[2];
    #pragma unroll
    for (int p = 0; p < 2; ++p) {
      float send = (c & 2) ? r1[2 * p] : r1[2 * p + 1];
      float recv = swz<0x081F>(send);
      float keep = (c & 2) ? r1[2 * p + 1] : r1[2 * p];
      r2[p] = keep + recv;
    }
    {
      float send = (c & 4) ? r2[0] : r2[1];
      float recv = swz<0x101F>(send);
      float keep = (c & 4) ? r2[1] : r2[0];
      float dot  = keep + recv;              // full dot for row == tid

      float pre = dot + xwv;
      float hni = tanhf(pre);
      xw_y[(size_t)t * BH + b * 512 + tid] = hni;   // y overwrites xw in place
      hbuf[nxt][(tid >> 6) * 72 + (tid & 63)] = (_Float16)hni;
      hlast = hni;
    }
    __syncthreads();
  }
  hn[b * 512 + tid] = hlast;
}

// ---------------------------------------------------------------------------
extern "C" void kernel_launch(void* const* d_in, const int* in_sizes, int n_in,
                              void* d_out, int out_size, void* d_ws, size_t ws_size,
                              hipStream_t stream) {
  const float* x   = (const float*)d_in[0];
  const float* h0  = (const float*)d_in[1];
  const float* Wih = (const float*)d_in[2];
  const float* Whh = (const float*)d_in[3];
  const float* bih = (const float*)d_in[4];
  const float* bhh = (const float*)d_in[5];
  float* out = (float*)d_out;
  float* ws  = (float*)d_ws;          // needs T*B*H*4 = 64 MiB
  float* hn  = out + (size_t)TBH;     // h_n area: [L, B, H]

  dim3 ggrid(256, 4), gblk(256);

  // layer 0: xw1 -> ws ; recur overwrites ws with y1 ; h_n[0]
  gemm_xw<<<ggrid, gblk, 0, stream>>>(x, Wih, bih, bhh, ws);
  recur<<<64, 512, 0, stream>>>(ws, h0, Whh, hn);

  // layer 1: xw2 -> out[0:TBH] ; recur overwrites with y2 (final out) ; h_n[1]
  gemm_xw<<<ggrid, gblk, 0, stream>>>(ws, Wih + (size_t)H_ * H_,
                                      bih + H_, bhh + H_, out);
  recur<<<64, 512, 0, stream>>>(out, h0 + BH, Whh + (size_t)H_ * H_, hn + BH);
}

// Round 3
// 1760.675 us; speedup vs baseline: 1.6894x; 1.6894x over previous
//
#include <hip/hip_runtime.h>
#include <stdint.h>

#define T_ 512
#define B_ 64
#define H_ 512
#define L_ 2
#define TBH (T_*B_*H_)   // 16777216
#define BH  (B_*H_)      // 32768

typedef float    f32x4 __attribute__((ext_vector_type(4)));
typedef short    s16x8 __attribute__((ext_vector_type(8)));
typedef short    s16x4 __attribute__((ext_vector_type(4)));
typedef _Float16 h2    __attribute__((ext_vector_type(2)));

static __device__ __forceinline__ short f2bf(float f) {
  uint32_t u = __float_as_uint(f);
  u = (u + 0x7fffu + ((u >> 16) & 1u)) >> 16;  // RNE
  return (short)u;
}

static __device__ __forceinline__ float fdot2(h2 a, h2 b, float c) {
#if __has_builtin(__builtin_amdgcn_fdot2)
  return __builtin_amdgcn_fdot2(a, b, c, false);
#else
  return c + (float)a[0] * (float)b[0] + (float)a[1] * (float)b[1];
#endif
}

template <int IMM>
static __device__ __forceinline__ float swz(float v) {
  return __int_as_float(__builtin_amdgcn_ds_swizzle(__float_as_int(v), IMM));
}

static __device__ __forceinline__ uint32_t pack2(float a, float b) {
  h2 p = { (_Float16)a, (_Float16)b };
  return __builtin_bit_cast(uint32_t, p);
}

// ---------------------------------------------------------------------------
// GEMM: Out[m,n] = sum_k In[m,k]*W[n,k] + bi[n] + bh[n]
// M=32768 (=T*B), N=512, K=512. bf16 MFMA 16x16x32, 128x128 tile, 4 waves.
// ---------------------------------------------------------------------------
__global__ __launch_bounds__(256, 4)
void gemm_xw(const float* __restrict__ In, const float* __restrict__ W,
             const float* __restrict__ bi, const float* __restrict__ bh,
             float* __restrict__ Out) {
  constexpr int LDT = 40;  // padded LDS stride in halves
  __shared__ short As[128 * LDT];
  __shared__ short Bs[128 * LDT];

  const int tid  = threadIdx.x;
  const int m0   = blockIdx.x * 128;
  const int n0   = blockIdx.y * 128;
  const int wave = tid >> 6, lane = tid & 63;
  const int wm   = (wave >> 1) * 64;
  const int wn   = (wave & 1) * 64;
  const int quad = lane >> 4, tq = lane & 15;

  f32x4 acc[4][4] = {};

  for (int k0 = 0; k0 < 512; k0 += 32) {
    #pragma unroll
    for (int v = 0; v < 4; ++v) {
      int idx = v * 256 + tid;
      int r = idx >> 3, cc = (idx & 7) * 4;
      f32x4 a = *(const f32x4*)(In + (size_t)(m0 + r) * 512 + k0 + cc);
      s16x4 ap = { f2bf(a.x), f2bf(a.y), f2bf(a.z), f2bf(a.w) };
      *(s16x4*)(&As[r * LDT + cc]) = ap;
      f32x4 b = *(const f32x4*)(W + (size_t)(n0 + r) * 512 + k0 + cc);
      s16x4 bp = { f2bf(b.x), f2bf(b.y), f2bf(b.z), f2bf(b.w) };
      *(s16x4*)(&Bs[r * LDT + cc]) = bp;
    }
    __syncthreads();

    s16x8 af[4], bfr[4];
    #pragma unroll
    for (int mf = 0; mf < 4; ++mf)
      af[mf] = *(const s16x8*)(&As[(wm + mf * 16 + tq) * LDT + quad * 8]);
    #pragma unroll
    for (int nf = 0; nf < 4; ++nf)
      bfr[nf] = *(const s16x8*)(&Bs[(wn + nf * 16 + tq) * LDT + quad * 8]);
    #pragma unroll
    for (int mf = 0; mf < 4; ++mf)
      #pragma unroll
      for (int nf = 0; nf < 4; ++nf)
        acc[mf][nf] = __builtin_amdgcn_mfma_f32_16x16x32_bf16(
            af[mf], bfr[nf], acc[mf][nf], 0, 0, 0);
    __syncthreads();
  }

  #pragma unroll
  for (int nf = 0; nf < 4; ++nf) {
    int col = n0 + wn + nf * 16 + tq;
    float bv = bi[col] + bh[col];
    #pragma unroll
    for (int mf = 0; mf < 4; ++mf) {
      #pragma unroll
      for (int r = 0; r < 4; ++r) {
        int row = m0 + wm + mf * 16 + quad * 4 + r;
        Out[(size_t)row * 512 + col] = acc[mf][nf][r] + bv;
      }
    }
  }
}

// ---------------------------------------------------------------------------
// Recurrence: 1 WG per batch, 512 threads, 2 waves/SIMD (256-VGPR budget).
// Thread t = rg*8 + c: rows rg*8..+7, columns c*64..+63.
// Weights: cols 0..47 of the chunk in VGPRs (fp16, 192 regs),
//          cols 48..63 in LDS (fp16, [row*2+part][tid] uint4 -> b128 reads).
// Per step: 256 v_dot2, butterfly over 8 lanes (xor 1,2,4) -> thread t owns
// row t. xw buffer overwritten in place with y.
// ---------------------------------------------------------------------------
__global__ __launch_bounds__(512)
__attribute__((amdgpu_waves_per_eu(2, 2)))
void recur(float* __restrict__ xw_y, const float* __restrict__ h0,
           const float* __restrict__ Wh, float* __restrict__ hn) {
  const int b   = blockIdx.x;
  const int tid = threadIdx.x;
  const int c   = tid & 7;
  const int rg  = tid >> 3;

  __shared__ uint4 wlds[16 * 512];            // 128 KiB: [k*2+p][tid]
  __shared__ _Float16 hbuf[2][8 * 72];        // chunk ci at ci*72 halves

  // --- weights: register part (cols 0..47 of chunk) ---
  h2 wreg[8][24];
  #pragma unroll
  for (int k = 0; k < 8; ++k) {
    const float* wrow = Wh + (size_t)(rg * 8 + k) * 512 + c * 64;
    #pragma unroll
    for (int u = 0; u < 6; ++u) {
      f32x4 w4 = *(const f32x4*)(wrow + u * 8);
      f32x4 w5 = *(const f32x4*)(wrow + u * 8 + 4);
      wreg[k][u * 4 + 0] = h2{(_Float16)w4.x, (_Float16)w4.y};
      wreg[k][u * 4 + 1] = h2{(_Float16)w4.z, (_Float16)w4.w};
      wreg[k][u * 4 + 2] = h2{(_Float16)w5.x, (_Float16)w5.y};
      wreg[k][u * 4 + 3] = h2{(_Float16)w5.z, (_Float16)w5.w};
    }
    // --- weights: LDS part (cols 48..63 of chunk) ---
    #pragma unroll
    for (int p = 0; p < 2; ++p) {
      f32x4 w4 = *(const f32x4*)(wrow + 48 + p * 8);
      f32x4 w5 = *(const f32x4*)(wrow + 48 + p * 8 + 4);
      uint4 pk;
      pk.x = pack2(w4.x, w4.y);
      pk.y = pack2(w4.z, w4.w);
      pk.z = pack2(w5.x, w5.y);
      pk.w = pack2(w5.z, w5.w);
      wlds[(k * 2 + p) * 512 + tid] = pk;
    }
  }

  hbuf[0][(tid >> 6) * 72 + (tid & 63)] = (_Float16)h0[b * 512 + tid];
  __syncthreads();

  float hlast = 0.f;
  for (int t = 0; t < T_; ++t) {
    const int cur = t & 1, nxt = cur ^ 1;
    float xwv = xw_y[(size_t)t * BH + b * 512 + tid];

    const _Float16* hc = &hbuf[cur][c * 72];
    float acc[8] = {0, 0, 0, 0, 0, 0, 0, 0};

    // ---- batch 1: h sub-chunks u=0..3 (reg weights) ----
    uint4 hv[4];
    #pragma unroll
    for (int u = 0; u < 4; ++u) hv[u] = *(const uint4*)(hc + u * 8);
    #pragma unroll
    for (int u = 0; u < 4; ++u) {
      h2 p0 = __builtin_bit_cast(h2, hv[u].x);
      h2 p1 = __builtin_bit_cast(h2, hv[u].y);
      h2 p2 = __builtin_bit_cast(h2, hv[u].z);
      h2 p3 = __builtin_bit_cast(h2, hv[u].w);
      #pragma unroll
      for (int k = 0; k < 8; ++k) {
        acc[k] = fdot2(wreg[k][u * 4 + 0], p0, acc[k]);
        acc[k] = fdot2(wreg[k][u * 4 + 1], p1, acc[k]);
        acc[k] = fdot2(wreg[k][u * 4 + 2], p2, acc[k]);
        acc[k] = fdot2(wreg[k][u * 4 + 3], p3, acc[k]);
      }
    }
    // ---- batch 2: h sub-chunks u=4..7 (reuse hv regs) ----
    #pragma unroll
    for (int u = 0; u < 4; ++u) hv[u] = *(const uint4*)(hc + 32 + u * 8);
    #pragma unroll
    for (int u = 0; u < 2; ++u) {            // u=4,5: reg weights
      h2 p0 = __builtin_bit_cast(h2, hv[u].x);
      h2 p1 = __builtin_bit_cast(h2, hv[u].y);
      h2 p2 = __builtin_bit_cast(h2, hv[u].z);
      h2 p3 = __builtin_bit_cast(h2, hv[u].w);
      #pragma unroll
      for (int k = 0; k < 8; ++k) {
        acc[k] = fdot2(wreg[k][(u + 4) * 4 + 0], p0, acc[k]);
        acc[k] = fdot2(wreg[k][(u + 4) * 4 + 1], p1, acc[k]);
        acc[k] = fdot2(wreg[k][(u + 4) * 4 + 2], p2, acc[k]);
        acc[k] = fdot2(wreg[k][(u + 4) * 4 + 3], p3, acc[k]);
      }
    }
    // ---- LDS-weight part: cols 48..63 (h sub-chunks u=6,7 = hv[2],hv[3]) ----
    {
      h2 q0 = __builtin_bit_cast(h2, hv[2].x);
      h2 q1 = __builtin_bit_cast(h2, hv[2].y);
      h2 q2 = __builtin_bit_cast(h2, hv[2].z);
      h2 q3 = __builtin_bit_cast(h2, hv[2].w);
      h2 r0 = __builtin_bit_cast(h2, hv[3].x);
      h2 r1 = __builtin_bit_cast(h2, hv[3].y);
      h2 r2 = __builtin_bit_cast(h2, hv[3].z);
      h2 r3 = __builtin_bit_cast(h2, hv[3].w);
      #pragma unroll
      for (int k = 0; k < 8; ++k) {
        uint4 w0 = wlds[(k * 2 + 0) * 512 + tid];
        uint4 w1 = wlds[(k * 2 + 1) * 512 + tid];
        acc[k] = fdot2(__builtin_bit_cast(h2, w0.x), q0, acc[k]);
        acc[k] = fdot2(__builtin_bit_cast(h2, w0.y), q1, acc[k]);
        acc[k] = fdot2(__builtin_bit_cast(h2, w0.z), q2, acc[k]);
        acc[k] = fdot2(__builtin_bit_cast(h2, w0.w), q3, acc[k]);
        acc[k] = fdot2(__builtin_bit_cast(h2, w1.x), r0, acc[k]);
        acc[k] = fdot2(__builtin_bit_cast(h2, w1.y), r1, acc[k]);
        acc[k] = fdot2(__builtin_bit_cast(h2, w1.z), r2, acc[k]);
        acc[k] = fdot2(__builtin_bit_cast(h2, w1.w), r3, acc[k]);
      }
    }

    // butterfly reduce across the 8 lanes of the row-group (lane xor 1,2,4)
    float r1v[4];
    #pragma unroll
    for (int p = 0; p < 4; ++p) {
      float send = (c & 1) ? acc[2 * p] : acc[2 * p + 1];
      float recv = swz<0x041F>(send);
      float keep = (c & 1) ? acc[2 * p + 1] : acc[2 * p];
      r1v[p] = keep + recv;
    }
    float r2v[2];
    #pragma unroll
    for (int p = 0; p < 2; ++p) {
      float send = (c & 2) ? r1v[2 * p] : r1v[2 * p + 1];
      float recv = swz<0x081F>(send);
      float keep = (c & 2) ? r1v[2 * p + 1] : r1v[2 * p];
      r2v[p] = keep + recv;
    }
    {
      float send = (c & 4) ? r2v[0] : r2v[1];
      float recv = swz<0x101F>(send);
      float keep = (c & 4) ? r2v[1] : r2v[0];
      float dot  = keep + recv;              // full dot for row == tid

      float pre = dot + xwv;
      float e   = __expf(2.f * pre);         // tanh = 1 - 2/(e^{2x}+1)
      float hni = 1.f - 2.f / (e + 1.f);
      xw_y[(size_t)t * BH + b * 512 + tid] = hni;
      hbuf[nxt][(tid >> 6) * 72 + (tid & 63)] = (_Float16)hni;
      hlast = hni;
    }
    __syncthreads();
  }
  hn[b * 512 + tid] = hlast;
}

// ---------------------------------------------------------------------------
extern "C" void kernel_launch(void* const* d_in, const int* in_sizes, int n_in,
                              void* d_out, int out_size, void* d_ws, size_t ws_size,
                              hipStream_t stream) {
  const float* x   = (const float*)d_in[0];
  const float* h0  = (const float*)d_in[1];
  const float* Wih = (const float*)d_in[2];
  const float* Whh = (const float*)d_in[3];
  const float* bih = (const float*)d_in[4];
  const float* bhh = (const float*)d_in[5];
  float* out = (float*)d_out;
  float* ws  = (float*)d_ws;          // needs T*B*H*4 = 64 MiB
  float* hn  = out + (size_t)TBH;     // h_n area: [L, B, H]

  dim3 ggrid(256, 4), gblk(256);

  gemm_xw<<<ggrid, gblk, 0, stream>>>(x, Wih, bih, bhh, ws);
  recur<<<64, 512, 0, stream>>>(ws, h0, Whh, hn);

  gemm_xw<<<ggrid, gblk, 0, stream>>>(ws, Wih + (size_t)H_ * H_,
                                      bih + H_, bhh + H_, out);
  recur<<<64, 512, 0, stream>>>(out, h0 + BH, Whh + (size_t)H_ * H_, hn + BH);
}

// Round 4
// 1754.865 us; speedup vs baseline: 1.6950x; 1.0033x over previous
//
#include <hip/hip_runtime.h>
#include <stdint.h>

#define T_ 512
#define B_ 64
#define H_ 512
#define L_ 2
#define TBH (T_*B_*H_)   // 16777216
#define BH  (B_*H_)      // 32768

typedef float    f32x4 __attribute__((ext_vector_type(4)));
typedef short    s16x8 __attribute__((ext_vector_type(8)));
typedef short    s16x4 __attribute__((ext_vector_type(4)));
typedef _Float16 h2    __attribute__((ext_vector_type(2)));

static __device__ __forceinline__ short f2bf(float f) {
  uint32_t u = __float_as_uint(f);
  u = (u + 0x7fffu + ((u >> 16) & 1u)) >> 16;  // RNE
  return (short)u;
}

static __device__ __forceinline__ float fdot2(h2 a, h2 b, float c) {
#if __has_builtin(__builtin_amdgcn_fdot2)
  return __builtin_amdgcn_fdot2(a, b, c, false);
#else
  return c + (float)a[0] * (float)b[0] + (float)a[1] * (float)b[1];
#endif
}

template <int IMM>
static __device__ __forceinline__ float swz(float v) {
  return __int_as_float(__builtin_amdgcn_ds_swizzle(__float_as_int(v), IMM));
}

static __device__ __forceinline__ uint32_t pack2(float a, float b) {
  h2 p = { (_Float16)a, (_Float16)b };
  return __builtin_bit_cast(uint32_t, p);
}

// ---------------------------------------------------------------------------
// GEMM: Out[m,n] = sum_k In[m,k]*W[n,k] + bi[n] + bh[n]
// M=32768 (=T*B), N=512, K=512. bf16 MFMA 16x16x32, 128x128 tile, 4 waves.
// ---------------------------------------------------------------------------
__global__ __launch_bounds__(256, 4)
void gemm_xw(const float* __restrict__ In, const float* __restrict__ W,
             const float* __restrict__ bi, const float* __restrict__ bh,
             float* __restrict__ Out) {
  constexpr int LDT = 40;  // padded LDS stride in halves
  __shared__ short As[128 * LDT];
  __shared__ short Bs[128 * LDT];

  const int tid  = threadIdx.x;
  const int m0   = blockIdx.x * 128;
  const int n0   = blockIdx.y * 128;
  const int wave = tid >> 6, lane = tid & 63;
  const int wm   = (wave >> 1) * 64;
  const int wn   = (wave & 1) * 64;
  const int quad = lane >> 4, tq = lane & 15;

  f32x4 acc[4][4] = {};

  for (int k0 = 0; k0 < 512; k0 += 32) {
    #pragma unroll
    for (int v = 0; v < 4; ++v) {
      int idx = v * 256 + tid;
      int r = idx >> 3, cc = (idx & 7) * 4;
      f32x4 a = *(const f32x4*)(In + (size_t)(m0 + r) * 512 + k0 + cc);
      s16x4 ap = { f2bf(a.x), f2bf(a.y), f2bf(a.z), f2bf(a.w) };
      *(s16x4*)(&As[r * LDT + cc]) = ap;
      f32x4 b = *(const f32x4*)(W + (size_t)(n0 + r) * 512 + k0 + cc);
      s16x4 bp = { f2bf(b.x), f2bf(b.y), f2bf(b.z), f2bf(b.w) };
      *(s16x4*)(&Bs[r * LDT + cc]) = bp;
    }
    __syncthreads();

    s16x8 af[4], bfr[4];
    #pragma unroll
    for (int mf = 0; mf < 4; ++mf)
      af[mf] = *(const s16x8*)(&As[(wm + mf * 16 + tq) * LDT + quad * 8]);
    #pragma unroll
    for (int nf = 0; nf < 4; ++nf)
      bfr[nf] = *(const s16x8*)(&Bs[(wn + nf * 16 + tq) * LDT + quad * 8]);
    #pragma unroll
    for (int mf = 0; mf < 4; ++mf)
      #pragma unroll
      for (int nf = 0; nf < 4; ++nf)
        acc[mf][nf] = __builtin_amdgcn_mfma_f32_16x16x32_bf16(
            af[mf], bfr[nf], acc[mf][nf], 0, 0, 0);
    __syncthreads();
  }

  #pragma unroll
  for (int nf = 0; nf < 4; ++nf) {
    int col = n0 + wn + nf * 16 + tq;
    float bv = bi[col] + bh[col];
    #pragma unroll
    for (int mf = 0; mf < 4; ++mf) {
      #pragma unroll
      for (int r = 0; r < 4; ++r) {
        int row = m0 + wm + mf * 16 + quad * 4 + r;
        Out[(size_t)row * 512 + col] = acc[mf][nf][r] + bv;
      }
    }
  }
}

// ---------------------------------------------------------------------------
// Recurrence: 1 WG per batch, 512 threads. __launch_bounds__(512,2): min
// 2 waves/EU -> 256-VGPR budget so wreg (192 VGPRs) stays in registers.
// (R3's amdgpu_waves_per_eu attribute was IGNORED: VGPR_Count=128, spilled.)
// Thread t = rg*8 + c: rows rg*8..+7, columns c*64..+63.
// Weights: cols 0..47 of the chunk in VGPRs (fp16, 192 regs),
//          cols 48..63 in LDS (fp16, [row*2+part][tid] uint4 -> b128 reads).
// Per step: 256 v_dot2, butterfly over 8 lanes (xor 1,2,4) -> thread t owns
// row t. xw buffer overwritten in place with y.
// ---------------------------------------------------------------------------
__global__ __launch_bounds__(512, 2)
void recur(float* __restrict__ xw_y, const float* __restrict__ h0,
           const float* __restrict__ Wh, float* __restrict__ hn) {
  const int b   = blockIdx.x;
  const int tid = threadIdx.x;
  const int c   = tid & 7;
  const int rg  = tid >> 3;

  __shared__ uint4 wlds[16 * 512];            // 128 KiB: [k*2+p][tid]
  __shared__ _Float16 hbuf[2][8 * 72];        // chunk ci at ci*72 halves

  // --- weights: register part (cols 0..47 of chunk) ---
  h2 wreg[8][24];
  #pragma unroll
  for (int k = 0; k < 8; ++k) {
    const float* wrow = Wh + (size_t)(rg * 8 + k) * 512 + c * 64;
    #pragma unroll
    for (int u = 0; u < 6; ++u) {
      f32x4 w4 = *(const f32x4*)(wrow + u * 8);
      f32x4 w5 = *(const f32x4*)(wrow + u * 8 + 4);
      wreg[k][u * 4 + 0] = h2{(_Float16)w4.x, (_Float16)w4.y};
      wreg[k][u * 4 + 1] = h2{(_Float16)w4.z, (_Float16)w4.w};
      wreg[k][u * 4 + 2] = h2{(_Float16)w5.x, (_Float16)w5.y};
      wreg[k][u * 4 + 3] = h2{(_Float16)w5.z, (_Float16)w5.w};
    }
    // --- weights: LDS part (cols 48..63 of chunk) ---
    #pragma unroll
    for (int p = 0; p < 2; ++p) {
      f32x4 w4 = *(const f32x4*)(wrow + 48 + p * 8);
      f32x4 w5 = *(const f32x4*)(wrow + 48 + p * 8 + 4);
      uint4 pk;
      pk.x = pack2(w4.x, w4.y);
      pk.y = pack2(w4.z, w4.w);
      pk.z = pack2(w5.x, w5.y);
      pk.w = pack2(w5.z, w5.w);
      wlds[(k * 2 + p) * 512 + tid] = pk;
    }
  }

  hbuf[0][(tid >> 6) * 72 + (tid & 63)] = (_Float16)h0[b * 512 + tid];
  __syncthreads();

  float hlast = 0.f;
  for (int t = 0; t < T_; ++t) {
    const int cur = t & 1, nxt = cur ^ 1;
    float xwv = xw_y[(size_t)t * BH + b * 512 + tid];

    const _Float16* hc = &hbuf[cur][c * 72];
    float acc[8] = {0, 0, 0, 0, 0, 0, 0, 0};

    // ---- batch 1: h sub-chunks u=0..3 (reg weights) ----
    uint4 hv[4];
    #pragma unroll
    for (int u = 0; u < 4; ++u) hv[u] = *(const uint4*)(hc + u * 8);
    #pragma unroll
    for (int u = 0; u < 4; ++u) {
      h2 p0 = __builtin_bit_cast(h2, hv[u].x);
      h2 p1 = __builtin_bit_cast(h2, hv[u].y);
      h2 p2 = __builtin_bit_cast(h2, hv[u].z);
      h2 p3 = __builtin_bit_cast(h2, hv[u].w);
      #pragma unroll
      for (int k = 0; k < 8; ++k) {
        acc[k] = fdot2(wreg[k][u * 4 + 0], p0, acc[k]);
        acc[k] = fdot2(wreg[k][u * 4 + 1], p1, acc[k]);
        acc[k] = fdot2(wreg[k][u * 4 + 2], p2, acc[k]);
        acc[k] = fdot2(wreg[k][u * 4 + 3], p3, acc[k]);
      }
    }
    // ---- batch 2: h sub-chunks u=4..7 (reuse hv regs) ----
    #pragma unroll
    for (int u = 0; u < 4; ++u) hv[u] = *(const uint4*)(hc + 32 + u * 8);
    #pragma unroll
    for (int u = 0; u < 2; ++u) {            // u=4,5: reg weights
      h2 p0 = __builtin_bit_cast(h2, hv[u].x);
      h2 p1 = __builtin_bit_cast(h2, hv[u].y);
      h2 p2 = __builtin_bit_cast(h2, hv[u].z);
      h2 p3 = __builtin_bit_cast(h2, hv[u].w);
      #pragma unroll
      for (int k = 0; k < 8; ++k) {
        acc[k] = fdot2(wreg[k][(u + 4) * 4 + 0], p0, acc[k]);
        acc[k] = fdot2(wreg[k][(u + 4) * 4 + 1], p1, acc[k]);
        acc[k] = fdot2(wreg[k][(u + 4) * 4 + 2], p2, acc[k]);
        acc[k] = fdot2(wreg[k][(u + 4) * 4 + 3], p3, acc[k]);
      }
    }
    // ---- LDS-weight part: cols 48..63 (h sub-chunks u=6,7 = hv[2],hv[3]) ----
    {
      h2 q0 = __builtin_bit_cast(h2, hv[2].x);
      h2 q1 = __builtin_bit_cast(h2, hv[2].y);
      h2 q2 = __builtin_bit_cast(h2, hv[2].z);
      h2 q3 = __builtin_bit_cast(h2, hv[2].w);
      h2 r0 = __builtin_bit_cast(h2, hv[3].x);
      h2 r1 = __builtin_bit_cast(h2, hv[3].y);
      h2 r2 = __builtin_bit_cast(h2, hv[3].z);
      h2 r3 = __builtin_bit_cast(h2, hv[3].w);
      #pragma unroll
      for (int k = 0; k < 8; ++k) {
        uint4 w0 = wlds[(k * 2 + 0) * 512 + tid];
        uint4 w1 = wlds[(k * 2 + 1) * 512 + tid];
        acc[k] = fdot2(__builtin_bit_cast(h2, w0.x), q0, acc[k]);
        acc[k] = fdot2(__builtin_bit_cast(h2, w0.y), q1, acc[k]);
        acc[k] = fdot2(__builtin_bit_cast(h2, w0.z), q2, acc[k]);
        acc[k] = fdot2(__builtin_bit_cast(h2, w0.w), q3, acc[k]);
        acc[k] = fdot2(__builtin_bit_cast(h2, w1.x), r0, acc[k]);
        acc[k] = fdot2(__builtin_bit_cast(h2, w1.y), r1, acc[k]);
        acc[k] = fdot2(__builtin_bit_cast(h2, w1.z), r2, acc[k]);
        acc[k] = fdot2(__builtin_bit_cast(h2, w1.w), r3, acc[k]);
      }
    }

    // butterfly reduce across the 8 lanes of the row-group (lane xor 1,2,4)
    float r1v[4];
    #pragma unroll
    for (int p = 0; p < 4; ++p) {
      float send = (c & 1) ? acc[2 * p] : acc[2 * p + 1];
      float recv = swz<0x041F>(send);
      float keep = (c & 1) ? acc[2 * p + 1] : acc[2 * p];
      r1v[p] = keep + recv;
    }
    float r2v[2];
    #pragma unroll
    for (int p = 0; p < 2; ++p) {
      float send = (c & 2) ? r1v[2 * p] : r1v[2 * p + 1];
      float recv = swz<0x081F>(send);
      float keep = (c & 2) ? r1v[2 * p + 1] : r1v[2 * p];
      r2v[p] = keep + recv;
    }
    {
      float send = (c & 4) ? r2v[0] : r2v[1];
      float recv = swz<0x101F>(send);
      float keep = (c & 4) ? r2v[1] : r2v[0];
      float dot  = keep + recv;              // full dot for row == tid

      float pre = dot + xwv;
      float e   = __expf(2.f * pre);         // tanh = 1 - 2/(e^{2x}+1)
      float hni = 1.f - 2.f / (e + 1.f);
      xw_y[(size_t)t * BH + b * 512 + tid] = hni;
      hbuf[nxt][(tid >> 6) * 72 + (tid & 63)] = (_Float16)hni;
      hlast = hni;
    }
    __syncthreads();
  }
  hn[b * 512 + tid] = hlast;
}

// ---------------------------------------------------------------------------
extern "C" void kernel_launch(void* const* d_in, const int* in_sizes, int n_in,
                              void* d_out, int out_size, void* d_ws, size_t ws_size,
                              hipStream_t stream) {
  const float* x   = (const float*)d_in[0];
  const float* h0  = (const float*)d_in[1];
  const float* Wih = (const float*)d_in[2];
  const float* Whh = (const float*)d_in[3];
  const float* bih = (const float*)d_in[4];
  const float* bhh = (const float*)d_in[5];
  float* out = (float*)d_out;
  float* ws  = (float*)d_ws;          // needs T*B*H*4 = 64 MiB
  float* hn  = out + (size_t)TBH;     // h_n area: [L, B, H]

  dim3 ggrid(256, 4), gblk(256);

  gemm_xw<<<ggrid, gblk, 0, stream>>>(x, Wih, bih, bhh, ws);
  recur<<<64, 512, 0, stream>>>(ws, h0, Whh, hn);

  gemm_xw<<<ggrid, gblk, 0, stream>>>(ws, Wih + (size_t)H_ * H_,
                                      bih + H_, bhh + H_, out);
  recur<<<64, 512, 0, stream>>>(out, h0 + BH, Whh + (size_t)H_ * H_, hn + BH);
}

// Round 5
// 1753.369 us; speedup vs baseline: 1.6965x; 1.0009x over previous
//
#include <hip/hip_runtime.h>
#include <stdint.h>

#define T_ 512
#define B_ 64
#define H_ 512
#define L_ 2
#define TBH (T_*B_*H_)   // 16777216
#define BH  (B_*H_)      // 32768

typedef float    f32x4 __attribute__((ext_vector_type(4)));
typedef short    s16x8 __attribute__((ext_vector_type(8)));
typedef short    s16x4 __attribute__((ext_vector_type(4)));
typedef _Float16 h2    __attribute__((ext_vector_type(2)));

static __device__ __forceinline__ short f2bf(float f) {
  uint32_t u = __float_as_uint(f);
  u = (u + 0x7fffu + ((u >> 16) & 1u)) >> 16;  // RNE
  return (short)u;
}

static __device__ __forceinline__ float fdot2(h2 a, h2 b, float c) {
#if __has_builtin(__builtin_amdgcn_fdot2)
  return __builtin_amdgcn_fdot2(a, b, c, false);
#else
  return c + (float)a[0] * (float)b[0] + (float)a[1] * (float)b[1];
#endif
}

template <int IMM>
static __device__ __forceinline__ float swz(float v) {
  return __int_as_float(__builtin_amdgcn_ds_swizzle(__float_as_int(v), IMM));
}

static __device__ __forceinline__ uint32_t pack2(float a, float b) {
  h2 p = { (_Float16)a, (_Float16)b };
  return __builtin_bit_cast(uint32_t, p);
}

// ---------------------------------------------------------------------------
// GEMM: Out[m,n] = sum_k In[m,k]*W[n,k] + bi[n] + bh[n]
// M=32768 (=T*B), N=512, K=512. bf16 MFMA 16x16x32, 128x128 tile, 4 waves.
// ---------------------------------------------------------------------------
__global__ __launch_bounds__(256, 4)
void gemm_xw(const float* __restrict__ In, const float* __restrict__ W,
             const float* __restrict__ bi, const float* __restrict__ bh,
             float* __restrict__ Out) {
  constexpr int LDT = 40;  // padded LDS stride in halves
  __shared__ short As[128 * LDT];
  __shared__ short Bs[128 * LDT];

  const int tid  = threadIdx.x;
  const int m0   = blockIdx.x * 128;
  const int n0   = blockIdx.y * 128;
  const int wave = tid >> 6, lane = tid & 63;
  const int wm   = (wave >> 1) * 64;
  const int wn   = (wave & 1) * 64;
  const int quad = lane >> 4, tq = lane & 15;

  f32x4 acc[4][4] = {};

  for (int k0 = 0; k0 < 512; k0 += 32) {
    #pragma unroll
    for (int v = 0; v < 4; ++v) {
      int idx = v * 256 + tid;
      int r = idx >> 3, cc = (idx & 7) * 4;
      f32x4 a = *(const f32x4*)(In + (size_t)(m0 + r) * 512 + k0 + cc);
      s16x4 ap = { f2bf(a.x), f2bf(a.y), f2bf(a.z), f2bf(a.w) };
      *(s16x4*)(&As[r * LDT + cc]) = ap;
      f32x4 b = *(const f32x4*)(W + (size_t)(n0 + r) * 512 + k0 + cc);
      s16x4 bp = { f2bf(b.x), f2bf(b.y), f2bf(b.z), f2bf(b.w) };
      *(s16x4*)(&Bs[r * LDT + cc]) = bp;
    }
    __syncthreads();

    s16x8 af[4], bfr[4];
    #pragma unroll
    for (int mf = 0; mf < 4; ++mf)
      af[mf] = *(const s16x8*)(&As[(wm + mf * 16 + tq) * LDT + quad * 8]);
    #pragma unroll
    for (int nf = 0; nf < 4; ++nf)
      bfr[nf] = *(const s16x8*)(&Bs[(wn + nf * 16 + tq) * LDT + quad * 8]);
    #pragma unroll
    for (int mf = 0; mf < 4; ++mf)
      #pragma unroll
      for (int nf = 0; nf < 4; ++nf)
        acc[mf][nf] = __builtin_amdgcn_mfma_f32_16x16x32_bf16(
            af[mf], bfr[nf], acc[mf][nf], 0, 0, 0);
    __syncthreads();
  }

  #pragma unroll
  for (int nf = 0; nf < 4; ++nf) {
    int col = n0 + wn + nf * 16 + tq;
    float bv = bi[col] + bh[col];
    #pragma unroll
    for (int mf = 0; mf < 4; ++mf) {
      #pragma unroll
      for (int r = 0; r < 4; ++r) {
        int row = m0 + wm + mf * 16 + quad * 4 + r;
        Out[(size_t)row * 512 + col] = acc[mf][nf][r] + bv;
      }
    }
  }
}

// ---------------------------------------------------------------------------
// Recurrence: 1 WG per batch, 512 threads.
// __launch_bounds__(512, 1): R4 showed (512,2) still yields a 128-VGPR
// budget — consistent with the 2nd arg being min BLOCKS/CU (CUDA semantics):
// 2 blocks x 8 waves = 4 waves/EU -> 128 regs. With arg=1, either semantics
// (1 block -> 2 waves/EU, or 1 wave/EU) allows >=256 VGPRs, so wreg
// (192 VGPRs) can stay in registers with no per-step re-materialization.
// Thread t = rg*8 + c: rows rg*8..+7, columns c*64..+63.
// Weights: cols 0..47 of the chunk in VGPRs (fp16, 192 regs),
//          cols 48..63 in LDS (fp16, [row*2+part][tid] uint4 -> b128 reads).
// Per step: 256 v_dot2, butterfly over 8 lanes (xor 1,2,4) -> thread t owns
// row t. xw buffer overwritten in place with y.
// ---------------------------------------------------------------------------
__global__ __launch_bounds__(512, 1)
void recur(float* __restrict__ xw_y, const float* __restrict__ h0,
           const float* __restrict__ Wh, float* __restrict__ hn) {
  const int b   = blockIdx.x;
  const int tid = threadIdx.x;
  const int c   = tid & 7;
  const int rg  = tid >> 3;

  __shared__ uint4 wlds[16 * 512];            // 128 KiB: [k*2+p][tid]
  __shared__ _Float16 hbuf[2][8 * 72];        // chunk ci at ci*72 halves

  // --- weights: register part (cols 0..47 of chunk) ---
  h2 wreg[8][24];
  #pragma unroll
  for (int k = 0; k < 8; ++k) {
    const float* wrow = Wh + (size_t)(rg * 8 + k) * 512 + c * 64;
    #pragma unroll
    for (int u = 0; u < 6; ++u) {
      f32x4 w4 = *(const f32x4*)(wrow + u * 8);
      f32x4 w5 = *(const f32x4*)(wrow + u * 8 + 4);
      wreg[k][u * 4 + 0] = h2{(_Float16)w4.x, (_Float16)w4.y};
      wreg[k][u * 4 + 1] = h2{(_Float16)w4.z, (_Float16)w4.w};
      wreg[k][u * 4 + 2] = h2{(_Float16)w5.x, (_Float16)w5.y};
      wreg[k][u * 4 + 3] = h2{(_Float16)w5.z, (_Float16)w5.w};
    }
    // --- weights: LDS part (cols 48..63 of chunk) ---
    #pragma unroll
    for (int p = 0; p < 2; ++p) {
      f32x4 w4 = *(const f32x4*)(wrow + 48 + p * 8);
      f32x4 w5 = *(const f32x4*)(wrow + 48 + p * 8 + 4);
      uint4 pk;
      pk.x = pack2(w4.x, w4.y);
      pk.y = pack2(w4.z, w4.w);
      pk.z = pack2(w5.x, w5.y);
      pk.w = pack2(w5.z, w5.w);
      wlds[(k * 2 + p) * 512 + tid] = pk;
    }
  }

  hbuf[0][(tid >> 6) * 72 + (tid & 63)] = (_Float16)h0[b * 512 + tid];
  __syncthreads();

  float hlast = 0.f;
  for (int t = 0; t < T_; ++t) {
    const int cur = t & 1, nxt = cur ^ 1;
    float xwv = xw_y[(size_t)t * BH + b * 512 + tid];

    const _Float16* hc = &hbuf[cur][c * 72];
    float acc[8] = {0, 0, 0, 0, 0, 0, 0, 0};

    // ---- batch 1: h sub-chunks u=0..3 (reg weights) ----
    uint4 hv[4];
    #pragma unroll
    for (int u = 0; u < 4; ++u) hv[u] = *(const uint4*)(hc + u * 8);
    #pragma unroll
    for (int u = 0; u < 4; ++u) {
      h2 p0 = __builtin_bit_cast(h2, hv[u].x);
      h2 p1 = __builtin_bit_cast(h2, hv[u].y);
      h2 p2 = __builtin_bit_cast(h2, hv[u].z);
      h2 p3 = __builtin_bit_cast(h2, hv[u].w);
      #pragma unroll
      for (int k = 0; k < 8; ++k) {
        acc[k] = fdot2(wreg[k][u * 4 + 0], p0, acc[k]);
        acc[k] = fdot2(wreg[k][u * 4 + 1], p1, acc[k]);
        acc[k] = fdot2(wreg[k][u * 4 + 2], p2, acc[k]);
        acc[k] = fdot2(wreg[k][u * 4 + 3], p3, acc[k]);
      }
    }
    // ---- batch 2: h sub-chunks u=4..7 (reuse hv regs) ----
    #pragma unroll
    for (int u = 0; u < 4; ++u) hv[u] = *(const uint4*)(hc + 32 + u * 8);
    #pragma unroll
    for (int u = 0; u < 2; ++u) {            // u=4,5: reg weights
      h2 p0 = __builtin_bit_cast(h2, hv[u].x);
      h2 p1 = __builtin_bit_cast(h2, hv[u].y);
      h2 p2 = __builtin_bit_cast(h2, hv[u].z);
      h2 p3 = __builtin_bit_cast(h2, hv[u].w);
      #pragma unroll
      for (int k = 0; k < 8; ++k) {
        acc[k] = fdot2(wreg[k][(u + 4) * 4 + 0], p0, acc[k]);
        acc[k] = fdot2(wreg[k][(u + 4) * 4 + 1], p1, acc[k]);
        acc[k] = fdot2(wreg[k][(u + 4) * 4 + 2], p2, acc[k]);
        acc[k] = fdot2(wreg[k][(u + 4) * 4 + 3], p3, acc[k]);
      }
    }
    // ---- LDS-weight part: cols 48..63 (h sub-chunks u=6,7 = hv[2],hv[3]) ----
    {
      h2 q0 = __builtin_bit_cast(h2, hv[2].x);
      h2 q1 = __builtin_bit_cast(h2, hv[2].y);
      h2 q2 = __builtin_bit_cast(h2, hv[2].z);
      h2 q3 = __builtin_bit_cast(h2, hv[2].w);
      h2 r0 = __builtin_bit_cast(h2, hv[3].x);
      h2 r1 = __builtin_bit_cast(h2, hv[3].y);
      h2 r2 = __builtin_bit_cast(h2, hv[3].z);
      h2 r3 = __builtin_bit_cast(h2, hv[3].w);
      #pragma unroll
      for (int k = 0; k < 8; ++k) {
        uint4 w0 = wlds[(k * 2 + 0) * 512 + tid];
        uint4 w1 = wlds[(k * 2 + 1) * 512 + tid];
        acc[k] = fdot2(__builtin_bit_cast(h2, w0.x), q0, acc[k]);
        acc[k] = fdot2(__builtin_bit_cast(h2, w0.y), q1, acc[k]);
        acc[k] = fdot2(__builtin_bit_cast(h2, w0.z), q2, acc[k]);
        acc[k] = fdot2(__builtin_bit_cast(h2, w0.w), q3, acc[k]);
        acc[k] = fdot2(__builtin_bit_cast(h2, w1.x), r0, acc[k]);
        acc[k] = fdot2(__builtin_bit_cast(h2, w1.y), r1, acc[k]);
        acc[k] = fdot2(__builtin_bit_cast(h2, w1.z), r2, acc[k]);
        acc[k] = fdot2(__builtin_bit_cast(h2, w1.w), r3, acc[k]);
      }
    }

    // butterfly reduce across the 8 lanes of the row-group (lane xor 1,2,4)
    float r1v[4];
    #pragma unroll
    for (int p = 0; p < 4; ++p) {
      float send = (c & 1) ? acc[2 * p] : acc[2 * p + 1];
      float recv = swz<0x041F>(send);
      float keep = (c & 1) ? acc[2 * p + 1] : acc[2 * p];
      r1v[p] = keep + recv;
    }
    float r2v[2];
    #pragma unroll
    for (int p = 0; p < 2; ++p) {
      float send = (c & 2) ? r1v[2 * p] : r1v[2 * p + 1];
      float recv = swz<0x081F>(send);
      float keep = (c & 2) ? r1v[2 * p + 1] : r1v[2 * p];
      r2v[p] = keep + recv;
    }
    {
      float send = (c & 4) ? r2v[0] : r2v[1];
      float recv = swz<0x101F>(send);
      float keep = (c & 4) ? r2v[1] : r2v[0];
      float dot  = keep + recv;              // full dot for row == tid

      float pre = dot + xwv;
      float e   = __expf(2.f * pre);         // tanh = 1 - 2/(e^{2x}+1)
      float hni = 1.f - 2.f / (e + 1.f);
      xw_y[(size_t)t * BH + b * 512 + tid] = hni;
      hbuf[nxt][(tid >> 6) * 72 + (tid & 63)] = (_Float16)hni;
      hlast = hni;
    }
    __syncthreads();
  }
  hn[b * 512 + tid] = hlast;
}

// ---------------------------------------------------------------------------
extern "C" void kernel_launch(void* const* d_in, const int* in_sizes, int n_in,
                              void* d_out, int out_size, void* d_ws, size_t ws_size,
                              hipStream_t stream) {
  const float* x   = (const float*)d_in[0];
  const float* h0  = (const float*)d_in[1];
  const float* Wih = (const float*)d_in[2];
  const float* Whh = (const float*)d_in[3];
  const float* bih = (const float*)d_in[4];
  const float* bhh = (const float*)d_in[5];
  float* out = (float*)d_out;
  float* ws  = (float*)d_ws;          // needs T*B*H*4 = 64 MiB
  float* hn  = out + (size_t)TBH;     // h_n area: [L, B, H]

  dim3 ggrid(256, 4), gblk(256);

  gemm_xw<<<ggrid, gblk, 0, stream>>>(x, Wih, bih, bhh, ws);
  recur<<<64, 512, 0, stream>>>(ws, h0, Whh, hn);

  gemm_xw<<<ggrid, gblk, 0, stream>>>(ws, Wih + (size_t)H_ * H_,
                                      bih + H_, bhh + H_, out);
  recur<<<64, 512, 0, stream>>>(out, h0 + BH, Whh + (size_t)H_ * H_, hn + BH);
}

// Round 7
// 1530.347 us; speedup vs baseline: 1.9437x; 1.1457x over previous
//
#include <hip/hip_runtime.h>
#include <stdint.h>

#define T_ 512
#define B_ 64
#define H_ 512
#define L_ 2
#define TBH (T_*B_*H_)   // 16777216
#define BH  (B_*H_)      // 32768
#define NC  8            // time chunks
#define CS  64           // steps per chunk
#define CROWS (CS*B_)    // 4096 rows of [T*B] per chunk

typedef float    f32x4 __attribute__((ext_vector_type(4)));
typedef short    s16x8 __attribute__((ext_vector_type(8)));
typedef short    s16x4 __attribute__((ext_vector_type(4)));
typedef _Float16 h2    __attribute__((ext_vector_type(2)));

static __device__ __forceinline__ short f2bf(float f) {
  uint32_t u = __float_as_uint(f);
  u = (u + 0x7fffu + ((u >> 16) & 1u)) >> 16;  // RNE
  return (short)u;
}

static __device__ __forceinline__ float fdot2(h2 a, h2 b, float c) {
#if __has_builtin(__builtin_amdgcn_fdot2)
  return __builtin_amdgcn_fdot2(a, b, c, false);
#else
  return c + (float)a[0] * (float)b[0] + (float)a[1] * (float)b[1];
#endif
}

template <int IMM>
static __device__ __forceinline__ float swz(float v) {
  return __int_as_float(__builtin_amdgcn_ds_swizzle(__float_as_int(v), IMM));
}

static __device__ __forceinline__ uint32_t pack2(float a, float b) {
  h2 p = { (_Float16)a, (_Float16)b };
  return __builtin_bit_cast(uint32_t, p);
}

// ---------------------------------------------------------------------------
// GEMM role (512 threads, 256x128 tile, 8 waves as 4Mx2N of 64x64):
// Out[m,n] = sum_k In[m,k]*W[n,k] + bi[n] + bh[n], for one 4096-row chunk.
// rb in [0,64): mt = rb>>2 (16 M-tiles), nt = rb&3 (4 N-tiles).
// ---------------------------------------------------------------------------
__device__ void gemm_role(char* smem, int rb,
                          const float* __restrict__ In,
                          const float* __restrict__ W,
                          const float* __restrict__ bi,
                          const float* __restrict__ bh,
                          float* __restrict__ Out) {
  constexpr int LDT = 40;
  short* As = (short*)smem;              // 256 x LDT
  short* Bs = (short*)(smem + 256 * LDT * 2);  // 128 x LDT

  const int tid  = threadIdx.x;
  const int m0   = (rb >> 2) * 256;
  const int n0   = (rb & 3) * 128;
  const int wave = tid >> 6, lane = tid & 63;
  const int wm   = (wave >> 1) * 64;   // 0,64,128,192
  const int wn   = (wave & 1) * 64;    // 0,64
  const int quad = lane >> 4, tq = lane & 15;

  f32x4 acc[4][4] = {};

  for (int k0 = 0; k0 < 512; k0 += 32) {
    #pragma unroll
    for (int v = 0; v < 4; ++v) {            // A: 256 rows x 8 float4
      int idx = v * 512 + tid;
      int r = idx >> 3, cc = (idx & 7) * 4;
      f32x4 a = *(const f32x4*)(In + (size_t)(m0 + r) * 512 + k0 + cc);
      s16x4 ap = { f2bf(a.x), f2bf(a.y), f2bf(a.z), f2bf(a.w) };
      *(s16x4*)(&As[r * LDT + cc]) = ap;
    }
    #pragma unroll
    for (int v = 0; v < 2; ++v) {            // B: 128 rows x 8 float4
      int idx = v * 512 + tid;
      int r = idx >> 3, cc = (idx & 7) * 4;
      f32x4 b = *(const f32x4*)(W + (size_t)(n0 + r) * 512 + k0 + cc);
      s16x4 bp = { f2bf(b.x), f2bf(b.y), f2bf(b.z), f2bf(b.w) };
      *(s16x4*)(&Bs[r * LDT + cc]) = bp;
    }
    __syncthreads();

    s16x8 af[4], bfr[4];
    #pragma unroll
    for (int mf = 0; mf < 4; ++mf)
      af[mf] = *(const s16x8*)(&As[(wm + mf * 16 + tq) * LDT + quad * 8]);
    #pragma unroll
    for (int nf = 0; nf < 4; ++nf)
      bfr[nf] = *(const s16x8*)(&Bs[(wn + nf * 16 + tq) * LDT + quad * 8]);
    #pragma unroll
    for (int mf = 0; mf < 4; ++mf)
      #pragma unroll
      for (int nf = 0; nf < 4; ++nf)
        acc[mf][nf] = __builtin_amdgcn_mfma_f32_16x16x32_bf16(
            af[mf], bfr[nf], acc[mf][nf], 0, 0, 0);
    __syncthreads();
  }

  #pragma unroll
  for (int nf = 0; nf < 4; ++nf) {
    int col = n0 + wn + nf * 16 + tq;
    float bv = bi[col] + bh[col];
    #pragma unroll
    for (int mf = 0; mf < 4; ++mf) {
      #pragma unroll
      for (int r = 0; r < 4; ++r) {
        int row = m0 + wm + mf * 16 + quad * 4 + r;
        Out[(size_t)row * 512 + col] = acc[mf][nf][r] + bv;
      }
    }
  }
}

// ---------------------------------------------------------------------------
// Recurrence role (one chunk of CS steps). 1 WG = 1 batch, 512 threads.
// Thread t = rg*8 + c: rows rg*8..+7, column chunk c*64..+63.
// Weights: cols 0..47 in regs (compiler splits arch/AGPR), cols 48..63 in
// LDS ([row*2+part][tid] uint4). Per step: 256 v_dot2, xor-1/2/4 butterfly
// -> thread t owns row t. xw buffer overwritten in place with y.
// h-state persists across chunk launches in hstate (fp32; bit-identical to
// the monolithic loop since hbuf is fp16 either way).
// ---------------------------------------------------------------------------
__device__ void recur_role(char* smem, int b, int chunk,
                           float* __restrict__ xw_y,
                           const float* __restrict__ h0l,
                           const float* __restrict__ Wh,
                           float* __restrict__ hstate) {
  const int tid = threadIdx.x;
  const int c   = tid & 7;
  const int rg  = tid >> 3;

  uint4*    wlds = (uint4*)smem;                     // 16*512 entries, 128 KiB
  _Float16* hbuf = (_Float16*)(smem + 131072);       // [2][8*72]

  h2 wreg[8][24];
  #pragma unroll
  for (int k = 0; k < 8; ++k) {
    const float* wrow = Wh + (size_t)(rg * 8 + k) * 512 + c * 64;
    #pragma unroll
    for (int u = 0; u < 6; ++u) {
      f32x4 w4 = *(const f32x4*)(wrow + u * 8);
      f32x4 w5 = *(const f32x4*)(wrow + u * 8 + 4);
      wreg[k][u * 4 + 0] = h2{(_Float16)w4.x, (_Float16)w4.y};
      wreg[k][u * 4 + 1] = h2{(_Float16)w4.z, (_Float16)w4.w};
      wreg[k][u * 4 + 2] = h2{(_Float16)w5.x, (_Float16)w5.y};
      wreg[k][u * 4 + 3] = h2{(_Float16)w5.z, (_Float16)w5.w};
    }
    #pragma unroll
    for (int p = 0; p < 2; ++p) {
      f32x4 w4 = *(const f32x4*)(wrow + 48 + p * 8);
      f32x4 w5 = *(const f32x4*)(wrow + 48 + p * 8 + 4);
      uint4 pk;
      pk.x = pack2(w4.x, w4.y);
      pk.y = pack2(w4.z, w4.w);
      pk.z = pack2(w5.x, w5.y);
      pk.w = pack2(w5.z, w5.w);
      wlds[(k * 2 + p) * 512 + tid] = pk;
    }
  }

  float hini = (chunk == 0) ? h0l[b * 512 + tid] : hstate[b * 512 + tid];
  hbuf[(tid >> 6) * 72 + (tid & 63)] = (_Float16)hini;   // parity 0 (t0 even)
  __syncthreads();

  const int t0 = chunk * CS;
  float hlast = 0.f;
  for (int t = t0; t < t0 + CS; ++t) {
    const int cur = t & 1, nxt = cur ^ 1;
    float xwv = xw_y[(size_t)t * BH + b * 512 + tid];

    const _Float16* hc = &hbuf[cur * 8 * 72 + c * 72];
    float acc[8] = {0, 0, 0, 0, 0, 0, 0, 0};

    uint4 hv[4];
    #pragma unroll
    for (int u = 0; u < 4; ++u) hv[u] = *(const uint4*)(hc + u * 8);
    #pragma unroll
    for (int u = 0; u < 4; ++u) {
      h2 p0 = __builtin_bit_cast(h2, hv[u].x);
      h2 p1 = __builtin_bit_cast(h2, hv[u].y);
      h2 p2 = __builtin_bit_cast(h2, hv[u].z);
      h2 p3 = __builtin_bit_cast(h2, hv[u].w);
      #pragma unroll
      for (int k = 0; k < 8; ++k) {
        acc[k] = fdot2(wreg[k][u * 4 + 0], p0, acc[k]);
        acc[k] = fdot2(wreg[k][u * 4 + 1], p1, acc[k]);
        acc[k] = fdot2(wreg[k][u * 4 + 2], p2, acc[k]);
        acc[k] = fdot2(wreg[k][u * 4 + 3], p3, acc[k]);
      }
    }
    #pragma unroll
    for (int u = 0; u < 4; ++u) hv[u] = *(const uint4*)(hc + 32 + u * 8);
    #pragma unroll
    for (int u = 0; u < 2; ++u) {            // u=4,5: reg weights
      h2 p0 = __builtin_bit_cast(h2, hv[u].x);
      h2 p1 = __builtin_bit_cast(h2, hv[u].y);
      h2 p2 = __builtin_bit_cast(h2, hv[u].z);
      h2 p3 = __builtin_bit_cast(h2, hv[u].w);
      #pragma unroll
      for (int k = 0; k < 8; ++k) {
        acc[k] = fdot2(wreg[k][(u + 4) * 4 + 0], p0, acc[k]);
        acc[k] = fdot2(wreg[k][(u + 4) * 4 + 1], p1, acc[k]);
        acc[k] = fdot2(wreg[k][(u + 4) * 4 + 2], p2, acc[k]);
        acc[k] = fdot2(wreg[k][(u + 4) * 4 + 3], p3, acc[k]);
      }
    }
    {   // cols 48..63 from LDS; h = hv[2], hv[3]
      h2 q0 = __builtin_bit_cast(h2, hv[2].x);
      h2 q1 = __builtin_bit_cast(h2, hv[2].y);
      h2 q2 = __builtin_bit_cast(h2, hv[2].z);
      h2 q3 = __builtin_bit_cast(h2, hv[2].w);
      h2 r0 = __builtin_bit_cast(h2, hv[3].x);
      h2 r1 = __builtin_bit_cast(h2, hv[3].y);
      h2 r2 = __builtin_bit_cast(h2, hv[3].z);
      h2 r3 = __builtin_bit_cast(h2, hv[3].w);
      #pragma unroll
      for (int k = 0; k < 8; ++k) {
        uint4 w0 = wlds[(k * 2 + 0) * 512 + tid];
        uint4 w1 = wlds[(k * 2 + 1) * 512 + tid];
        acc[k] = fdot2(__builtin_bit_cast(h2, w0.x), q0, acc[k]);
        acc[k] = fdot2(__builtin_bit_cast(h2, w0.y), q1, acc[k]);
        acc[k] = fdot2(__builtin_bit_cast(h2, w0.z), q2, acc[k]);
        acc[k] = fdot2(__builtin_bit_cast(h2, w0.w), q3, acc[k]);
        acc[k] = fdot2(__builtin_bit_cast(h2, w1.x), r0, acc[k]);
        acc[k] = fdot2(__builtin_bit_cast(h2, w1.y), r1, acc[k]);
        acc[k] = fdot2(__builtin_bit_cast(h2, w1.z), r2, acc[k]);
        acc[k] = fdot2(__builtin_bit_cast(h2, w1.w), r3, acc[k]);
      }
    }

    float r1v[4];
    #pragma unroll
    for (int p = 0; p < 4; ++p) {
      float send = (c & 1) ? acc[2 * p] : acc[2 * p + 1];
      float recv = swz<0x041F>(send);
      float keep = (c & 1) ? acc[2 * p + 1] : acc[2 * p];
      r1v[p] = keep + recv;
    }
    float r2v[2];
    #pragma unroll
    for (int p = 0; p < 2; ++p) {
      float send = (c & 2) ? r1v[2 * p] : r1v[2 * p + 1];
      float recv = swz<0x081F>(send);
      float keep = (c & 2) ? r1v[2 * p + 1] : r1v[2 * p];
      r2v[p] = keep + recv;
    }
    {
      float send = (c & 4) ? r2v[0] : r2v[1];
      float recv = swz<0x101F>(send);
      float keep = (c & 4) ? r2v[1] : r2v[0];
      float dot  = keep + recv;              // full dot for row == tid

      float pre = dot + xwv;
      float e   = __expf(2.f * pre);         // tanh = 1 - 2/(e^{2x}+1)
      float hni = 1.f - 2.f / (e + 1.f);
      xw_y[(size_t)t * BH + b * 512 + tid] = hni;
      hbuf[nxt * 8 * 72 + (tid >> 6) * 72 + (tid & 63)] = (_Float16)hni;
      hlast = hni;
    }
    __syncthreads();
  }
  hstate[b * 512 + tid] = hlast;   // final chunk leaves h_n in place
}

// ---------------------------------------------------------------------------
// Pipeline stage s (depth-3 software pipeline over 8 time-chunks):
//   blocks   0..63  R1: recur layer-0, chunk s        (0 <= s <= 7)
//   blocks  64..127 R2: recur layer-1, chunk s-2      (2 <= s <= 9)
//   blocks 128..191 G1: gemm x@W1^T,  chunk s+1       (-1 <= s <= 6)
//   blocks 192..255 G2: gemm y1@W2^T, chunk s-1       (1 <= s <= 8)
// Launched for s = -1..9 (11 launches). Cross-launch visibility via stream
// ordering. h-states live in the hn output slots (final chunk = h_n).
// ---------------------------------------------------------------------------
__global__ __launch_bounds__(512, 1)
void stage(int s,
           const float* __restrict__ x, const float* __restrict__ h0,
           const float* __restrict__ Wih, const float* __restrict__ Whh,
           const float* __restrict__ bih, const float* __restrict__ bhh,
           float* __restrict__ ws, float* __restrict__ out) {
  __shared__ __align__(16) char smem[133376];  // 128K wlds + 2.25K hbuf
  const int role = blockIdx.x >> 6;
  const int rb   = blockIdx.x & 63;
  float* hn = out + (size_t)TBH;

  if (role == 0) {                    // R1
    int cc = s;
    if (cc < 0 || cc >= NC) return;
    recur_role(smem, rb, cc, ws, h0, Whh, hn);
  } else if (role == 1) {             // R2
    int cc = s - 2;
    if (cc < 0 || cc >= NC) return;
    recur_role(smem, rb, cc, out, h0 + BH, Whh + (size_t)H_ * H_, hn + BH);
  } else if (role == 2) {             // G1
    int cc = s + 1;
    if (cc < 0 || cc >= NC) return;
    gemm_role(smem, rb, x + (size_t)cc * CROWS * 512, Wih, bih, bhh,
              ws + (size_t)cc * CROWS * 512);
  } else {                            // G2
    int cc = s - 1;
    if (cc < 0 || cc >= NC) return;
    gemm_role(smem, rb, ws + (size_t)cc * CROWS * 512,
              Wih + (size_t)H_ * H_, bih + H_, bhh + H_,
              out + (size_t)cc * CROWS * 512);
  }
}

// ---------------------------------------------------------------------------
extern "C" void kernel_launch(void* const* d_in, const int* in_sizes, int n_in,
                              void* d_out, int out_size, void* d_ws, size_t ws_size,
                              hipStream_t stream) {
  const float* x   = (const float*)d_in[0];
  const float* h0  = (const float*)d_in[1];
  const float* Wih = (const float*)d_in[2];
  const float* Whh = (const float*)d_in[3];
  const float* bih = (const float*)d_in[4];
  const float* bhh = (const float*)d_in[5];
  float* out = (float*)d_out;
  float* ws  = (float*)d_ws;          // T*B*H*4 = 64 MiB (xw1/y1)

  for (int s = -1; s <= NC + 1; ++s)
    stage<<<256, 512, 0, stream>>>(s, x, h0, Wih, Whh, bih, bhh, ws, out);
}